// Round 1
// baseline (1946.436 us; speedup 1.0000x reference)
//
#include <hip/hip_runtime.h>
#include <hip/hip_bf16.h>
#include <stdint.h>

// fSRN: fused SIREN + 3 forward-mode tangent streams.
// Layout: WG = 512 threads (8 waves), 64 points.
//   rows 0..63   = primal h      (waves 0,1)
//   rows 64..127 = tangent dh_x  (waves 2,3)
//   rows 128..191= tangent dh_y  (waves 4,5)
//   rows 192..255= tangent dh_z  (waves 6,7)
// Each wave owns 32 rows; per-lane register layout follows the MFMA
// 16x16x32 C-fragment (col = lane&15, row = (lane>>4)*4 + j) so the
// VALU GEMM can be swapped for v_mfma_f32_16x16x32_bf16 later.

#define OMEGA_C 30.0f

constexpr int NPTS = 131072;
constexpr int FDIM = 128;
constexpr int NBLK = 3;
constexpr int P_WG = 64;    // points per workgroup
constexpr int NTHR = 512;   // 8 waves
constexpr int RS   = 132;   // LDS row stride in bf16 elems (128 + 4 pad -> 264B rows)

__device__ __forceinline__ uint16_t bfbits(float f) {
    union { float f; uint32_t u; } x; x.f = f;
    uint32_t u = x.u;
    uint32_t r = (u + 0x7FFFu + ((u >> 16) & 1u)) >> 16;   // RNE
    return (uint16_t)r;
}
__device__ __forceinline__ float u16tof(uint16_t h) {
    union { uint32_t u; float f; } x; x.u = ((uint32_t)h) << 16; return x.f;
}
__device__ __forceinline__ float bflo(uint32_t u) {
    union { uint32_t u; float f; } x; x.u = u << 16; return x.f;
}
__device__ __forceinline__ float bfhi(uint32_t u) {
    union { uint32_t u; float f; } x; x.u = u & 0xFFFF0000u; return x.f;
}

__global__ __launch_bounds__(NTHR, 2) void fsrn_kernel(
    const float* __restrict__ coords,
    const float* __restrict__ first_w,
    const float* __restrict__ first_b,
    const float* __restrict__ res_w1,
    const float* __restrict__ res_b1,
    const float* __restrict__ res_w2,
    const float* __restrict__ res_b2,
    const float* __restrict__ final_w,
    float* __restrict__ out)
{
    __shared__ uint16_t A_lds[4 * P_WG * RS];   // 67584 B  (bf16 activations, per-wave regions)
    __shared__ uint16_t W_lds[FDIM * RS];       // 33792 B  (bf16 weights, current layer)
    __shared__ uint16_t C_lds[2 * P_WG * RS];   // 33792 B  (bf16 OMEGA*cos(pre), ping-pong)
    __shared__ float    xyz[P_WG * 3];          // 768 B
    __shared__ float    outp[3][P_WG][3];       // 2304 B

    const int tid    = threadIdx.x;
    const int wave   = tid >> 6;
    const int lane   = tid & 63;
    const int l15    = lane & 15;
    const int lq     = lane >> 4;          // 0..3
    const int stream = wave >> 1;          // 0 = primal, 1..3 = tangent k+1
    const int phalf  = (wave & 1) * 32;    // point offset of this wave's half
    const int rowbase= wave * 32;          // first A row owned by this wave
    const int pt0    = blockIdx.x * P_WG;

    float mst[2][8][4];   // master state (h for primal, dh for tangents), fp32
    float acc[2][8][4];   // GEMM accumulator

    // ---- stage coords ----
    if (tid < P_WG * 3) xyz[tid] = coords[pt0 * 3 + tid];
    __syncthreads();

    // ---- first layer: pre = O*(c@fw^T + fb); h = sin(pre); dh_k = O*cos(pre)*fw[f][k]
    #pragma unroll
    for (int nt = 0; nt < 8; ++nt) {
        const int f = nt * 16 + l15;
        const float w0 = first_w[f*3+0], w1 = first_w[f*3+1], w2 = first_w[f*3+2];
        const float fb = first_b[f];
        const float wk = (stream > 0) ? first_w[f*3 + (stream-1)] : 0.0f;
        #pragma unroll
        for (int mt = 0; mt < 2; ++mt) {
            #pragma unroll
            for (int j = 0; j < 4; ++j) {
                const int p = phalf + mt*16 + lq*4 + j;
                const float pre = OMEGA_C * (xyz[p*3]*w0 + xyz[p*3+1]*w1 + xyz[p*3+2]*w2 + fb);
                float v;
                if (stream == 0) v = __sinf(pre);
                else             v = OMEGA_C * __cosf(pre) * wk;
                mst[mt][nt][j] = v;
                A_lds[(rowbase + mt*16 + lq*4 + j) * RS + f] = bfbits(v);
            }
        }
    }

    // stage weights into LDS (bf16, scale folded)
    auto stageW = [&](const float* __restrict__ src, float scale) {
        #pragma unroll
        for (int i = 0; i < 8; ++i) {
            const int u   = (tid << 3) + i;      // 8B-unit index, 0..4095
            const int f   = u >> 5;
            const int pos = u & 31;
            const float4 v = *reinterpret_cast<const float4*>(src + (u << 2));
            uint2 w;
            w.x = (uint32_t)bfbits(scale*v.x) | ((uint32_t)bfbits(scale*v.y) << 16);
            w.y = (uint32_t)bfbits(scale*v.z) | ((uint32_t)bfbits(scale*v.w) << 16);
            *reinterpret_cast<uint2*>(&W_lds[f*RS + (pos << 2)]) = w;
        }
    };

    // GEMM: acc[r][f] = sum_g A[r][g] * W[f][g]   (own 32 rows only)
    auto gemm = [&]() {
        #pragma unroll
        for (int mt = 0; mt < 2; ++mt)
            #pragma unroll
            for (int nt = 0; nt < 8; ++nt)
                #pragma unroll
                for (int j = 0; j < 4; ++j) acc[mt][nt][j] = 0.0f;
        #pragma unroll 1
        for (int gb = 0; gb < FDIM; gb += 4) {
            float wf[8][4];
            #pragma unroll
            for (int nt = 0; nt < 8; ++nt) {
                const uint2 wv = *reinterpret_cast<const uint2*>(&W_lds[(nt*16 + l15)*RS + gb]);
                wf[nt][0] = bflo(wv.x); wf[nt][1] = bfhi(wv.x);
                wf[nt][2] = bflo(wv.y); wf[nt][3] = bfhi(wv.y);
            }
            #pragma unroll
            for (int mt = 0; mt < 2; ++mt) {
                float af[4][4];
                #pragma unroll
                for (int j = 0; j < 4; ++j) {
                    const uint2 av = *reinterpret_cast<const uint2*>(
                        &A_lds[(rowbase + mt*16 + lq*4 + j)*RS + gb]);
                    af[j][0] = bflo(av.x); af[j][1] = bfhi(av.x);
                    af[j][2] = bflo(av.y); af[j][3] = bfhi(av.y);
                }
                #pragma unroll
                for (int nt = 0; nt < 8; ++nt)
                    #pragma unroll
                    for (int j = 0; j < 4; ++j)
                        acc[mt][nt][j] += af[j][0]*wf[nt][0] + af[j][1]*wf[nt][1]
                                        + af[j][2]*wf[nt][2] + af[j][3]*wf[nt][3];
            }
        }
    };

    __syncthreads();                 // A (first layer) not needed cross-wave, but W next
    stageW(res_w1, 1.0f);            // block 0, layer 1 (s=1)
    __syncthreads();

    #pragma unroll 1
    for (int b = 0; b < NBLK; ++b) {
        // ---------- sub-layer 1: W = s*w1[b] ----------
        gemm();
        if (stream == 0) {
            #pragma unroll
            for (int nt = 0; nt < 8; ++nt) {
                const int f = nt*16 + l15;
                const float ob = OMEGA_C * res_b1[b*FDIM + f];
                #pragma unroll
                for (int mt = 0; mt < 2; ++mt) {
                    #pragma unroll
                    for (int j = 0; j < 4; ++j) {
                        const int p = phalf + mt*16 + lq*4 + j;
                        const float pre = OMEGA_C * acc[mt][nt][j] + ob;
                        const float sv = __sinf(pre);
                        const float cv = OMEGA_C * __cosf(pre);
                        C_lds[p*RS + f] = bfbits(cv);
                        A_lds[(rowbase + mt*16 + lq*4 + j)*RS + f] = bfbits(sv);
                    }
                }
            }
        }
        __syncthreads();   // cos factors visible; all waves done with w1[b]
        if (stream > 0) {
            #pragma unroll
            for (int nt = 0; nt < 8; ++nt) {
                const int f = nt*16 + l15;
                #pragma unroll
                for (int mt = 0; mt < 2; ++mt) {
                    #pragma unroll
                    for (int j = 0; j < 4; ++j) {
                        const int p = phalf + mt*16 + lq*4 + j;
                        const float cv = u16tof(C_lds[p*RS + f]);
                        const float dv = cv * acc[mt][nt][j];
                        A_lds[(rowbase + mt*16 + lq*4 + j)*RS + f] = bfbits(dv);
                    }
                }
            }
        }
        stageW(res_w2 + b*FDIM*FDIM, 1.0f);
        __syncthreads();   // W = w2[b] ready; A fully updated

        // ---------- sub-layer 2: W = w2[b], residual add ----------
        gemm();
        if (stream == 0) {
            #pragma unroll
            for (int nt = 0; nt < 8; ++nt) {
                const int f = nt*16 + l15;
                const float ob = OMEGA_C * res_b2[b*FDIM + f];
                #pragma unroll
                for (int mt = 0; mt < 2; ++mt) {
                    #pragma unroll
                    for (int j = 0; j < 4; ++j) {
                        const int p = phalf + mt*16 + lq*4 + j;
                        const float pre = OMEGA_C * acc[mt][nt][j] + ob;
                        const float sv = __sinf(pre);
                        const float cv = OMEGA_C * __cosf(pre);
                        C_lds[P_WG*RS + p*RS + f] = bfbits(cv);
                        mst[mt][nt][j] += sv;                       // h += s2 (fp32 master)
                        A_lds[(rowbase + mt*16 + lq*4 + j)*RS + f] = bfbits(mst[mt][nt][j]);
                    }
                }
            }
        }
        __syncthreads();
        if (stream > 0) {
            #pragma unroll
            for (int nt = 0; nt < 8; ++nt) {
                const int f = nt*16 + l15;
                #pragma unroll
                for (int mt = 0; mt < 2; ++mt) {
                    #pragma unroll
                    for (int j = 0; j < 4; ++j) {
                        const int p = phalf + mt*16 + lq*4 + j;
                        const float cv = u16tof(C_lds[P_WG*RS + p*RS + f]);
                        mst[mt][nt][j] += cv * acc[mt][nt][j];      // dh += ds2 (fp32 master)
                        A_lds[(rowbase + mt*16 + lq*4 + j)*RS + f] = bfbits(mst[mt][nt][j]);
                    }
                }
            }
        }
        if (b < NBLK-1) stageW(res_w1 + (b+1)*FDIM*FDIM, 0.5f);   // s=0.5 folded into w1
        __syncthreads();
    }

    // ---------- final: out[:,c] = signed combos of dh_k . final_w[row] ----------
    // out0 = dh0.fw0 + dh1.fw3 - dh2.fw2
    // out1 = dh1.fw0 + dh2.fw1 - dh0.fw3
    // out2 = dh2.fw0 + dh0.fw2 - dh1.fw1
    if (stream > 0) {
        const int k = stream - 1;
        int   wrs[3]; float sgs[3];
        if (k == 0)      { wrs[0]=0; sgs[0]= 1.f; wrs[1]=3; sgs[1]=-1.f; wrs[2]=2; sgs[2]= 1.f; }
        else if (k == 1) { wrs[0]=3; sgs[0]= 1.f; wrs[1]=0; sgs[1]= 1.f; wrs[2]=1; sgs[2]=-1.f; }
        else             { wrs[0]=2; sgs[0]=-1.f; wrs[1]=1; sgs[1]= 1.f; wrs[2]=0; sgs[2]= 1.f; }
        #pragma unroll
        for (int c = 0; c < 3; ++c) {
            const int wr = wrs[c]; const float sg = sgs[c];
            float fwv[8];
            #pragma unroll
            for (int nt = 0; nt < 8; ++nt) fwv[nt] = final_w[wr*FDIM + nt*16 + l15];
            #pragma unroll
            for (int mt = 0; mt < 2; ++mt) {
                #pragma unroll
                for (int j = 0; j < 4; ++j) {
                    float part = 0.0f;
                    #pragma unroll
                    for (int nt = 0; nt < 8; ++nt) part += mst[mt][nt][j] * fwv[nt];
                    part += __shfl_xor(part, 1);
                    part += __shfl_xor(part, 2);
                    part += __shfl_xor(part, 4);
                    part += __shfl_xor(part, 8);
                    if (l15 == 0) outp[k][phalf + mt*16 + lq*4 + j][c] = sg * part;
                }
            }
        }
    }
    __syncthreads();
    if (tid < P_WG * 3) {
        const int p = tid / 3, c = tid % 3;
        out[(pt0 + p)*3 + c] = outp[0][p][c] + outp[1][p][c] + outp[2][p][c];
    }
}

extern "C" void kernel_launch(void* const* d_in, const int* in_sizes, int n_in,
                              void* d_out, int out_size, void* d_ws, size_t ws_size,
                              hipStream_t stream) {
    const float* coords  = (const float*)d_in[0];
    const float* first_w = (const float*)d_in[1];
    const float* first_b = (const float*)d_in[2];
    const float* res_w1  = (const float*)d_in[3];
    const float* res_b1  = (const float*)d_in[4];
    const float* res_w2  = (const float*)d_in[5];
    const float* res_b2  = (const float*)d_in[6];
    const float* final_w = (const float*)d_in[7];
    // final_b (d_in[8]) does not influence the Jacobian -> unused.

    dim3 grid(NPTS / P_WG);   // 2048 workgroups
    fsrn_kernel<<<grid, NTHR, 0, stream>>>(coords, first_w, first_b,
                                           res_w1, res_b1, res_w2, res_b2,
                                           final_w, (float*)d_out);
}

// Round 2
// 485.089 us; speedup vs baseline: 4.0125x; 4.0125x over previous
//
#include <hip/hip_runtime.h>
#include <hip/hip_bf16.h>
#include <stdint.h>

// fSRN: fused SIREN + 3 forward-mode tangent streams, MFMA engine.
// WG = 512 threads (8 waves), 64 points.
//   rows 0..63   = primal h      (waves 0,1)
//   rows 64..127 = tangent dh_x  (waves 2,3)
//   rows 128..191= tangent dh_y  (waves 4,5)
//   rows 192..255= tangent dh_z  (waves 6,7)
// Each wave owns 32 rows of the 256x128 activation matrix; GEMM per wave =
// 2(mt) x 8(nt) x 4(kk) v_mfma_f32_16x16x32_bf16.  C/D fragment layout:
// col = lane&15, row = (lane>>4)*4 + j  (matches mst/acc indexing).
// A/B fragment: lane&15 = row/col, k = (lane>>4)*8 + 0..7 (one ds_read_b128).

#define OMEGA_C 30.0f

constexpr int NPTS = 131072;
constexpr int FDIM = 128;
constexpr int NBLK = 3;
constexpr int P_WG = 64;    // points per workgroup
constexpr int NTHR = 512;   // 8 waves
constexpr int RS   = 136;   // bf16 row stride: 272 B rows -> 16B-aligned frags
constexpr int RSC  = 132;   // f32 row stride for pre-activation exchange

typedef short bf16x8 __attribute__((ext_vector_type(8)));
typedef float f32x4  __attribute__((ext_vector_type(4)));

__device__ __forceinline__ uint16_t bfbits(float f) {
    union { float f; uint32_t u; } x; x.f = f;
    uint32_t u = x.u;
    uint32_t r = (u + 0x7FFFu + ((u >> 16) & 1u)) >> 16;   // RNE
    return (uint16_t)r;
}

__global__ __launch_bounds__(NTHR, 2) void fsrn_kernel(
    const float* __restrict__ coords,
    const float* __restrict__ first_w,
    const float* __restrict__ first_b,
    const float* __restrict__ res_w1,
    const float* __restrict__ res_b1,
    const float* __restrict__ res_w2,
    const float* __restrict__ res_b2,
    const float* __restrict__ final_w,
    float* __restrict__ out)
{
    __shared__ uint16_t A_lds[4 * P_WG * RS];   // 69632 B  bf16 activations
    __shared__ uint16_t W_lds[FDIM * RS];       // 34816 B  bf16 weights (current layer)
    __shared__ float    C_lds[P_WG * RSC];      // 33792 B  fp32 pre-activations
    __shared__ float    xyz[P_WG * 3];          // 768 B
    __shared__ float    outp[3][P_WG][3];       // 2304 B

    const int tid    = threadIdx.x;
    const int wave   = tid >> 6;
    const int lane   = tid & 63;
    const int l15    = lane & 15;
    const int lq     = lane >> 4;          // 0..3
    const int stream = wave >> 1;          // 0 = primal, 1..3 = tangent k+1
    const int phalf  = (wave & 1) * 32;    // point offset of this wave's half
    const int rowbase= wave * 32;          // first A row owned by this wave
    const int pt0    = blockIdx.x * P_WG;

    float mst[2][8][4];   // master state (h / dh), fp32
    f32x4 acc[2][8];      // MFMA accumulators; acc[mt][nt][j]

    // ---- stage coords ----
    if (tid < P_WG * 3) xyz[tid] = coords[pt0 * 3 + tid];
    __syncthreads();

    // ---- first layer ----
    #pragma unroll
    for (int nt = 0; nt < 8; ++nt) {
        const int f = nt * 16 + l15;
        const float w0 = first_w[f*3+0], w1 = first_w[f*3+1], w2 = first_w[f*3+2];
        const float fb = first_b[f];
        const float wk = (stream > 0) ? first_w[f*3 + (stream-1)] : 0.0f;
        #pragma unroll
        for (int mt = 0; mt < 2; ++mt) {
            #pragma unroll
            for (int j = 0; j < 4; ++j) {
                const int p = phalf + mt*16 + lq*4 + j;
                const float pre = OMEGA_C * (xyz[p*3]*w0 + xyz[p*3+1]*w1 + xyz[p*3+2]*w2 + fb);
                float v;
                if (stream == 0) v = __sinf(pre);
                else             v = OMEGA_C * __cosf(pre) * wk;
                mst[mt][nt][j] = v;
                A_lds[(rowbase + mt*16 + lq*4 + j) * RS + f] = bfbits(v);
            }
        }
    }

    // stage weights into LDS (bf16, scale folded)
    auto stageW = [&](const float* __restrict__ src, float scale) {
        #pragma unroll
        for (int i = 0; i < 8; ++i) {
            const int u   = (tid << 3) + i;      // 8B-unit index, 0..4095
            const int f   = u >> 5;
            const int pos = u & 31;
            const float4 v = *reinterpret_cast<const float4*>(src + (u << 2));
            uint2 w;
            w.x = (uint32_t)bfbits(scale*v.x) | ((uint32_t)bfbits(scale*v.y) << 16);
            w.y = (uint32_t)bfbits(scale*v.z) | ((uint32_t)bfbits(scale*v.w) << 16);
            *reinterpret_cast<uint2*>(&W_lds[f*RS + (pos << 2)]) = w;
        }
    };

    // MFMA GEMM: acc[r][f] = sum_g A[r][g] * W[f][g]  (own 32 rows)
    auto gemm = [&]() {
        #pragma unroll
        for (int mt = 0; mt < 2; ++mt)
            #pragma unroll
            for (int nt = 0; nt < 8; ++nt) acc[mt][nt] = f32x4{0.f, 0.f, 0.f, 0.f};
        #pragma unroll
        for (int kk = 0; kk < 4; ++kk) {
            bf16x8 af[2];
            #pragma unroll
            for (int mt = 0; mt < 2; ++mt)
                af[mt] = *reinterpret_cast<const bf16x8*>(
                    &A_lds[(rowbase + mt*16 + l15)*RS + kk*32 + lq*8]);
            #pragma unroll
            for (int nt = 0; nt < 8; ++nt) {
                const bf16x8 bf = *reinterpret_cast<const bf16x8*>(
                    &W_lds[(nt*16 + l15)*RS + kk*32 + lq*8]);
                acc[0][nt] = __builtin_amdgcn_mfma_f32_16x16x32_bf16(af[0], bf, acc[0][nt], 0, 0, 0);
                acc[1][nt] = __builtin_amdgcn_mfma_f32_16x16x32_bf16(af[1], bf, acc[1][nt], 0, 0, 0);
            }
        }
    };

    __syncthreads();
    stageW(res_w1, 1.0f);            // block 0, layer 1 (s=1)
    __syncthreads();

    #pragma unroll 1
    for (int b = 0; b < NBLK; ++b) {
        // ---------- sub-layer 1: W = s*w1[b] ----------
        gemm();
        if (stream == 0) {           // publish fp32 pre-activations (cheap)
            #pragma unroll
            for (int nt = 0; nt < 8; ++nt) {
                const int f = nt*16 + l15;
                const float ob = OMEGA_C * res_b1[b*FDIM + f];
                #pragma unroll
                for (int mt = 0; mt < 2; ++mt)
                    #pragma unroll
                    for (int j = 0; j < 4; ++j) {
                        const float pre = OMEGA_C * acc[mt][nt][j] + ob;
                        acc[mt][nt][j] = pre;
                        C_lds[(phalf + mt*16 + lq*4 + j)*RSC + f] = pre;
                    }
            }
        }
        __syncthreads();
        // all streams apply their nonlinearity in parallel
        #pragma unroll
        for (int nt = 0; nt < 8; ++nt) {
            const int f = nt*16 + l15;
            #pragma unroll
            for (int mt = 0; mt < 2; ++mt)
                #pragma unroll
                for (int j = 0; j < 4; ++j) {
                    float v;
                    if (stream == 0) {
                        v = __sinf(acc[mt][nt][j]);
                    } else {
                        const float pre = C_lds[(phalf + mt*16 + lq*4 + j)*RSC + f];
                        v = OMEGA_C * __cosf(pre) * acc[mt][nt][j];
                    }
                    A_lds[(rowbase + mt*16 + lq*4 + j)*RS + f] = bfbits(v);
                }
        }
        stageW(res_w2 + b*FDIM*FDIM, 1.0f);
        __syncthreads();

        // ---------- sub-layer 2: W = w2[b], residual add ----------
        gemm();
        if (stream == 0) {
            #pragma unroll
            for (int nt = 0; nt < 8; ++nt) {
                const int f = nt*16 + l15;
                const float ob = OMEGA_C * res_b2[b*FDIM + f];
                #pragma unroll
                for (int mt = 0; mt < 2; ++mt)
                    #pragma unroll
                    for (int j = 0; j < 4; ++j) {
                        const float pre = OMEGA_C * acc[mt][nt][j] + ob;
                        acc[mt][nt][j] = pre;
                        C_lds[(phalf + mt*16 + lq*4 + j)*RSC + f] = pre;
                    }
            }
        }
        __syncthreads();
        #pragma unroll
        for (int nt = 0; nt < 8; ++nt) {
            const int f = nt*16 + l15;
            #pragma unroll
            for (int mt = 0; mt < 2; ++mt)
                #pragma unroll
                for (int j = 0; j < 4; ++j) {
                    float m = mst[mt][nt][j];
                    if (stream == 0) {
                        m += __sinf(acc[mt][nt][j]);
                    } else {
                        const float pre = C_lds[(phalf + mt*16 + lq*4 + j)*RSC + f];
                        m += OMEGA_C * __cosf(pre) * acc[mt][nt][j];
                    }
                    mst[mt][nt][j] = m;
                    A_lds[(rowbase + mt*16 + lq*4 + j)*RS + f] = bfbits(m);
                }
        }
        if (b < NBLK-1) stageW(res_w1 + (b+1)*FDIM*FDIM, 0.5f);   // s=0.5 folded
        __syncthreads();
    }

    // ---------- final: out[:,c] = signed combos of dh_k . final_w[row] ----------
    // out0 = dh0.fw0 - dh2.fw3 + dh1.fw2   (see derivation in round 0)
    if (stream > 0) {
        const int k = stream - 1;
        int   wrs[3]; float sgs[3];
        if (k == 0)      { wrs[0]=0; sgs[0]= 1.f; wrs[1]=3; sgs[1]=-1.f; wrs[2]=2; sgs[2]= 1.f; }
        else if (k == 1) { wrs[0]=3; sgs[0]= 1.f; wrs[1]=0; sgs[1]= 1.f; wrs[2]=1; sgs[2]=-1.f; }
        else             { wrs[0]=2; sgs[0]=-1.f; wrs[1]=1; sgs[1]= 1.f; wrs[2]=0; sgs[2]= 1.f; }
        #pragma unroll
        for (int c = 0; c < 3; ++c) {
            const int wr = wrs[c]; const float sg = sgs[c];
            float fwv[8];
            #pragma unroll
            for (int nt = 0; nt < 8; ++nt) fwv[nt] = final_w[wr*FDIM + nt*16 + l15];
            #pragma unroll
            for (int mt = 0; mt < 2; ++mt) {
                #pragma unroll
                for (int j = 0; j < 4; ++j) {
                    float part = 0.0f;
                    #pragma unroll
                    for (int nt = 0; nt < 8; ++nt) part += mst[mt][nt][j] * fwv[nt];
                    part += __shfl_xor(part, 1);
                    part += __shfl_xor(part, 2);
                    part += __shfl_xor(part, 4);
                    part += __shfl_xor(part, 8);
                    if (l15 == 0) outp[k][phalf + mt*16 + lq*4 + j][c] = sg * part;
                }
            }
        }
    }
    __syncthreads();
    if (tid < P_WG * 3) {
        const int p = tid / 3, c = tid % 3;
        out[(pt0 + p)*3 + c] = outp[0][p][c] + outp[1][p][c] + outp[2][p][c];
    }
}

extern "C" void kernel_launch(void* const* d_in, const int* in_sizes, int n_in,
                              void* d_out, int out_size, void* d_ws, size_t ws_size,
                              hipStream_t stream) {
    const float* coords  = (const float*)d_in[0];
    const float* first_w = (const float*)d_in[1];
    const float* first_b = (const float*)d_in[2];
    const float* res_w1  = (const float*)d_in[3];
    const float* res_b1  = (const float*)d_in[4];
    const float* res_w2  = (const float*)d_in[5];
    const float* res_b2  = (const float*)d_in[6];
    const float* final_w = (const float*)d_in[7];
    // final_b (d_in[8]) does not influence the Jacobian -> unused.

    dim3 grid(NPTS / P_WG);   // 2048 workgroups
    fsrn_kernel<<<grid, NTHR, 0, stream>>>(coords, first_w, first_b,
                                           res_w1, res_b1, res_w2, res_b2,
                                           final_w, (float*)d_out);
}